// Round 1
// baseline (505.477 us; speedup 1.0000x reference)
//
#include <hip/hip_runtime.h>
#include <hip/hip_bf16.h>

// Problem constants
#define BB 256
#define TT 1024
#define II 128
#define HH 64

typedef float  f32x4_t __attribute__((ext_vector_type(4)));
typedef short  s16x8_t __attribute__((ext_vector_type(8)));

__device__ __forceinline__ unsigned short f2bf(float f){
  unsigned u = __float_as_uint(f);
  u += 0x7FFFu + ((u >> 16) & 1u);          // round-to-nearest-even
  return (unsigned short)(u >> 16);
}
__device__ __forceinline__ float bf2f(unsigned short s){
  return __uint_as_float(((unsigned)s) << 16);
}
__device__ __forceinline__ float tanh_fast(float x){
  // tanh(x) = 1 - 2/(1+e^{2x});  e^{2x} = exp2(x * 2/ln2)
  float e = __builtin_amdgcn_exp2f(x * 2.88539004f);
  return __builtin_fmaf(-2.0f, __builtin_amdgcn_rcpf(1.0f + e), 1.0f);
}

// ---------------------------------------------------------------------------
// K1: build W_comm (64x64 fp32) and combined bias into ws floats.
//     wsf[0..4095] = W_comm row-major; wsf[4096..4159] = W_in_b + bias
// ---------------------------------------------------------------------------
__global__ void k_prep(const float* __restrict__ Ap, const float* __restrict__ Am,
                       const float* __restrict__ Winb, const float* __restrict__ bias,
                       float* __restrict__ wsf){
  for (int e = threadIdx.x; e < 4096; e += blockDim.x){
    int i = e >> 6, j = e & 63;
    int is = i ^ 32, js = j ^ 32;
    float wp = Ap[i*64+j] + Ap[i*64+js] + Ap[is*64+j] + Ap[is*64+js];
    float wm = Am[i*64+j] - Am[i*64+js] - Am[is*64+j] + Am[is*64+js];
    wsf[e] = 0.25f * (wp + wm);
  }
  if (threadIdx.x < 64) wsf[4096 + threadIdx.x] = Winb[threadIdx.x] + bias[threadIdx.x];
}

// ---------------------------------------------------------------------------
// K2: U[b*T+t][h] = x[b,t,:] . W_in[h,:] + bc[h], stored bf16.
//     MFMA 16x16x32 bf16. Block = 256 thr (4 waves), 256 rows/block.
//     Each wave: 64 rows (4 m-tiles) x 64 cols (4 n-tiles), K = 128 (4 ksteps).
//     B-fragments (W_in^T) held in registers; bias folded into acc init.
// ---------------------------------------------------------------------------
__global__ __launch_bounds__(256) void k_inproj(const float* __restrict__ x,
                                                const float* __restrict__ Win,
                                                const float* __restrict__ wsf,
                                                unsigned short* __restrict__ U){
  const int lane = threadIdx.x & 63;
  const int wave = threadIdx.x >> 6;
  const int l15  = lane & 15;   // A: m-row, B: n-col, C: n-col
  const int q    = lane >> 4;   // A/B: k-chunk, C: m-row-quad

  // B fragments: B[k][n] = Win[n][k]; lane holds k = ks*32 + q*8 + j, n = nt*16 + l15
  s16x8_t bfr[4][4]; // [ks][nt]
  #pragma unroll
  for (int nt = 0; nt < 4; ++nt){
    #pragma unroll
    for (int ks = 0; ks < 4; ++ks){
      const float* src = Win + (nt*16 + l15) * II + ks*32 + q*8;
      float4 f0 = *(const float4*)(src);
      float4 f1 = *(const float4*)(src + 4);
      s16x8_t v;
      v[0]=(short)f2bf(f0.x); v[1]=(short)f2bf(f0.y); v[2]=(short)f2bf(f0.z); v[3]=(short)f2bf(f0.w);
      v[4]=(short)f2bf(f1.x); v[5]=(short)f2bf(f1.y); v[6]=(short)f2bf(f1.z); v[7]=(short)f2bf(f1.w);
      bfr[ks][nt] = v;
    }
  }
  float bcv[4];
  #pragma unroll
  for (int nt = 0; nt < 4; ++nt) bcv[nt] = wsf[4096 + nt*16 + l15];

  const long rowbase = (long)blockIdx.x * 256 + (long)wave * 64;

  #pragma unroll 1
  for (int mt = 0; mt < 4; ++mt){
    const long rb = rowbase + mt*16;
    const float* xa = x + (rb + l15) * II + q*8;
    s16x8_t afr[4];
    #pragma unroll
    for (int ks = 0; ks < 4; ++ks){
      float4 a0 = *(const float4*)(xa + ks*32);
      float4 a1 = *(const float4*)(xa + ks*32 + 4);
      s16x8_t v;
      v[0]=(short)f2bf(a0.x); v[1]=(short)f2bf(a0.y); v[2]=(short)f2bf(a0.z); v[3]=(short)f2bf(a0.w);
      v[4]=(short)f2bf(a1.x); v[5]=(short)f2bf(a1.y); v[6]=(short)f2bf(a1.z); v[7]=(short)f2bf(a1.w);
      afr[ks] = v;
    }
    f32x4_t acc[4];
    #pragma unroll
    for (int nt = 0; nt < 4; ++nt){
      acc[nt][0]=bcv[nt]; acc[nt][1]=bcv[nt]; acc[nt][2]=bcv[nt]; acc[nt][3]=bcv[nt];
    }
    #pragma unroll
    for (int ks = 0; ks < 4; ++ks){
      #pragma unroll
      for (int nt = 0; nt < 4; ++nt){
        acc[nt] = __builtin_amdgcn_mfma_f32_16x16x32_bf16(afr[ks], bfr[ks][nt], acc[nt], 0, 0, 0);
      }
    }
    // C layout: col = lane&15 (n), row = q*4 + r (m)
    #pragma unroll
    for (int nt = 0; nt < 4; ++nt){
      #pragma unroll
      for (int r = 0; r < 4; ++r){
        U[(rb + q*4 + r) * HH + nt*16 + l15] = f2bf(acc[nt][r]);
      }
    }
  }
}

// ---------------------------------------------------------------------------
// K3: sequential recurrence, one wave per batch. Lane i owns W_comm row i
//     (64 VGPRs) and h[i]. Per step: broadcast h[j] via v_readlane (VALU pipe,
//     no LDS, no barrier), 64 fmacs in 4 chains, fast tanh. u prefetched
//     4 steps ahead. Epilogue: predictions + final hidden.
// ---------------------------------------------------------------------------
__global__ __launch_bounds__(64) void k_rnn(const float* __restrict__ wsf,
                                            const unsigned short* __restrict__ U,
                                            const float* __restrict__ Wout,
                                            const float* __restrict__ Woutb,
                                            float* __restrict__ out){
  const int b    = blockIdx.x;
  const int lane = threadIdx.x;

  float w[64];
  {
    const float4* wr = (const float4*)(wsf + lane * 64);
    #pragma unroll
    for (int j4 = 0; j4 < 16; ++j4){
      float4 v = wr[j4];
      w[4*j4+0] = v.x; w[4*j4+1] = v.y; w[4*j4+2] = v.z; w[4*j4+3] = v.w;
    }
  }

  const unsigned short* Ub = U + (long)b * (TT * HH) + lane;
  float uc[4], un[4];
  #pragma unroll
  for (int g = 0; g < 4; ++g) uc[g] = bf2f(Ub[g * HH]);

  float h = 0.0f;
  for (int tg = 0; tg < TT/4; ++tg){
    // prefetch next group (distance = 4 steps)
    const int tn = (tg + 1) * 4;
    #pragma unroll
    for (int g = 0; g < 4; ++g){
      int t = tn + g; if (t > TT-1) t = TT-1;
      un[g] = bf2f(Ub[t * HH]);
    }
    #pragma unroll
    for (int g = 0; g < 4; ++g){
      float a0 = uc[g], a1 = 0.0f, a2 = 0.0f, a3 = 0.0f;
      unsigned hu = __float_as_uint(h);
      #pragma unroll
      for (int j = 0; j < 64; j += 4){
        a0 = __builtin_fmaf(w[j+0], __uint_as_float(__builtin_amdgcn_readlane(hu, j+0)), a0);
        a1 = __builtin_fmaf(w[j+1], __uint_as_float(__builtin_amdgcn_readlane(hu, j+1)), a1);
        a2 = __builtin_fmaf(w[j+2], __uint_as_float(__builtin_amdgcn_readlane(hu, j+2)), a2);
        a3 = __builtin_fmaf(w[j+3], __uint_as_float(__builtin_amdgcn_readlane(hu, j+3)), a3);
      }
      h = tanh_fast((a0 + a1) + (a2 + a3));
    }
    #pragma unroll
    for (int g = 0; g < 4; ++g) uc[g] = un[g];
  }

  // Epilogue: predictions[b] = W_out @ h + W_out_b ; hidden[b] = h
  unsigned hu = __float_as_uint(h);
  float p0 = Woutb[lane];
  float p1 = Woutb[lane + 64];
  #pragma unroll 8
  for (int j = 0; j < 64; ++j){
    float hj = __uint_as_float(__builtin_amdgcn_readlane(hu, j));
    p0 = __builtin_fmaf(Wout[lane * HH + j],        hj, p0);
    p1 = __builtin_fmaf(Wout[(lane + 64) * HH + j], hj, p1);
  }
  out[b * 128 + lane]       = p0;
  out[b * 128 + 64 + lane]  = p1;
  out[BB * 128 + b * 64 + lane] = h;
}

// ---------------------------------------------------------------------------
extern "C" void kernel_launch(void* const* d_in, const int* in_sizes, int n_in,
                              void* d_out, int out_size, void* d_ws, size_t ws_size,
                              hipStream_t stream){
  const float* x     = (const float*)d_in[0];
  const float* Ap    = (const float*)d_in[1];
  const float* Am    = (const float*)d_in[2];
  const float* Winw  = (const float*)d_in[3];
  const float* Winb  = (const float*)d_in[4];
  const float* Woutw = (const float*)d_in[5];
  const float* Woutb = (const float*)d_in[6];
  const float* bias  = (const float*)d_in[7];

  float*          wsf = (float*)d_ws;
  unsigned short* U   = (unsigned short*)((char*)d_ws + 32768);  // needs ~33.6 MB total
  float*          out = (float*)d_out;

  hipLaunchKernelGGL(k_prep,   dim3(1),    dim3(256), 0, stream, Ap, Am, Winb, bias, wsf);
  hipLaunchKernelGGL(k_inproj, dim3(1024), dim3(256), 0, stream, x, Winw, wsf, U);
  hipLaunchKernelGGL(k_rnn,    dim3(BB),   dim3(64),  0, stream, wsf, U, Woutw, Woutb, out);
}